// Round 3
// baseline (597.363 us; speedup 1.0000x reference)
//
#include <hip/hip_runtime.h>
#include <math.h>

#define BB 32
#define TT 2048
#define DD 1024
#define TCHUNK 64

// fast tanh via hardware exp: tanh(x) = 1 - 2/(e^{2x}+1)
// saturates correctly at +-inf; |err| ~1e-7 mid-range (threshold 2.3e-2).
__device__ __forceinline__ float fast_tanh(float x) {
    float e = __expf(2.0f * x);
    return 1.0f - __fdividef(2.0f, e + 1.0f);
}

// ---------------- kernel 1: eraw[b,t] = v . tanh(keys + query + wf) -------
// one WAVE per t (4 t per block); wave-shuffle reduce only. Raw energies go
// to d_ws (NOT d_out) so kernel 2 can read them while writing weights.
// Block x==0 also zeroes context[b,:] (kernel 2 accumulates via atomics).
__global__ __launch_bounds__(256) void energies_kernel(
    const float* __restrict__ keys, const float* __restrict__ query,
    const float* __restrict__ wf, const float* __restrict__ v,
    const int* __restrict__ lenp, float* __restrict__ eraw,
    float* __restrict__ context)
{
    const int b    = blockIdx.y;
    const int wave = threadIdx.x >> 6;
    const int lane = threadIdx.x & 63;
    const int t    = blockIdx.x * 4 + wave;

    if (blockIdx.x == 0) {   // zero context row before any exit (all threads)
        *(float4*)(context + (size_t)b * DD + threadIdx.x * 4) =
            make_float4(0.f, 0.f, 0.f, 0.f);
    }
    if (t >= lenp[b]) return;            // wave-uniform exit

    const size_t row  = ((size_t)b * TT + t) * DD;
    const size_t qrow = (size_t)b * DD;

    float s = 0.0f;
    #pragma unroll
    for (int k = 0; k < 4; k++) {
        const int d = k * 256 + lane * 4;
        const float4 k4 = *(const float4*)(keys + row + d);
        const float4 w4 = *(const float4*)(wf   + row + d);
        const float4 q4 = *(const float4*)(query + qrow + d);
        const float4 v4 = *(const float4*)(v + d);
        s += fast_tanh(k4.x + q4.x + w4.x) * v4.x
           + fast_tanh(k4.y + q4.y + w4.y) * v4.y
           + fast_tanh(k4.z + q4.z + w4.z) * v4.z
           + fast_tanh(k4.w + q4.w + w4.w) * v4.w;
    }
    #pragma unroll
    for (int off = 32; off > 0; off >>= 1) s += __shfl_down(s, off, 64);
    if (lane == 0) eraw[(size_t)b * TT + t] = s;
}

// ---- kernel 2: fused softmax + context -----------------------------------
// grid (TT/TCHUNK, BB). Each block re-computes the row max m and denom l from
// eraw (8 KiB, L2-hot), writes final weights for its own chunk, and
// accumulates w*value into context via atomics. Chunks past len write zero
// weights and exit without touching value.
__global__ __launch_bounds__(256) void ctx_softmax_kernel(
    const float* __restrict__ value, const float* __restrict__ eraw,
    const int* __restrict__ lenp, float* __restrict__ weights,
    float* __restrict__ context)
{
    const int b  = blockIdx.y;
    const int L  = lenp[b];
    const int t0 = blockIdx.x * TCHUNK;
    float* wrow = weights + (size_t)b * TT;

    if (t0 >= L) {                       // fully masked chunk: zero weights
        if (threadIdx.x < TCHUNK) wrow[t0 + threadIdx.x] = 0.0f;
        return;
    }

    const float* erow = eraw + (size_t)b * TT;
    const int wv   = threadIdx.x >> 6;
    const int lane = threadIdx.x & 63;

    // block-reduce max over t < L
    float m = -INFINITY;
    #pragma unroll
    for (int i = 0; i < 8; i++) {
        const int t = threadIdx.x + i * 256;
        if (t < L) m = fmaxf(m, erow[t]);
    }
    #pragma unroll
    for (int off = 1; off < 64; off <<= 1) m = fmaxf(m, __shfl_xor(m, off, 64));
    __shared__ float redm[4];
    if (lane == 0) redm[wv] = m;
    __syncthreads();
    m = fmaxf(fmaxf(redm[0], redm[1]), fmaxf(redm[2], redm[3]));

    // block-reduce sum of exp(e - m) over t < L
    float s = 0.0f;
    #pragma unroll
    for (int i = 0; i < 8; i++) {
        const int t = threadIdx.x + i * 256;
        if (t < L) s += __expf(erow[t] - m);
    }
    #pragma unroll
    for (int off = 1; off < 64; off <<= 1) s += __shfl_xor(s, off, 64);
    __shared__ float reds[4];
    if (lane == 0) reds[wv] = s;
    __syncthreads();
    s = reds[0] + reds[1] + reds[2] + reds[3];
    const float inv = 1.0f / s;

    // own chunk's weights -> LDS + global
    __shared__ float wsh[TCHUNK];
    if (threadIdx.x < TCHUNK) {
        const int t = t0 + threadIdx.x;
        const float w = (t < L) ? __expf(erow[t] - m) * inv : 0.0f;
        wsh[threadIdx.x] = w;
        wrow[t] = w;
    }
    __syncthreads();

    const int tend = min(t0 + TCHUNK, L);
    const int d = threadIdx.x * 4;
    float4 acc = make_float4(0.f, 0.f, 0.f, 0.f);
    #pragma unroll 2
    for (int t = t0; t < tend; t++) {
        const float w = wsh[t - t0];
        const float4 v4 = *(const float4*)(value + ((size_t)b * TT + t) * DD + d);
        acc.x += w * v4.x; acc.y += w * v4.y;
        acc.z += w * v4.z; acc.w += w * v4.w;
    }
    float* dst = context + (size_t)b * DD + d;
    atomicAdd(dst + 0, acc.x);
    atomicAdd(dst + 1, acc.y);
    atomicAdd(dst + 2, acc.z);
    atomicAdd(dst + 3, acc.w);
}

extern "C" void kernel_launch(void* const* d_in, const int* in_sizes, int n_in,
                              void* d_out, int out_size, void* d_ws, size_t ws_size,
                              hipStream_t stream) {
    const float* keys  = (const float*)d_in[0];
    const float* value = (const float*)d_in[1];
    const float* query = (const float*)d_in[2];
    const float* wf    = (const float*)d_in[3];
    const float* v     = (const float*)d_in[4];
    const int*   lenp  = (const int*)d_in[5];

    float* out      = (float*)d_out;
    float* context  = out;               // [B, D]
    float* weights  = out + BB * DD;     // [B, T] (weights[:,:,None] flattened)
    float* eraw     = (float*)d_ws;      // [B, T] raw energies scratch

    energies_kernel<<<dim3(TT / 4, BB), 256, 0, stream>>>(
        keys, query, wf, v, lenp, eraw, context);
    ctx_softmax_kernel<<<dim3(TT / TCHUNK, BB), 256, 0, stream>>>(
        value, eraw, lenp, weights, context);
}